// Round 3
// baseline (4798.250 us; speedup 1.0000x reference)
//
#include <hip/hip_runtime.h>

#define Bn 512
#define Tn 512
#define Dn 64
#define Hn 128
#define Ln 32

typedef __attribute__((ext_vector_type(8))) short short8v;
typedef __attribute__((ext_vector_type(4))) float float4v;

__device__ __forceinline__ unsigned short f2bf(float f){
  unsigned int u = __float_as_uint(f);
  u += 0x7FFFu + ((u >> 16) & 1u);           // round-to-nearest-even
  return (unsigned short)(u >> 16);
}

__device__ __forceinline__ short8v pack8(float4v a, float4v b){
  short8v r;
  r[0]=(short)f2bf(a[0]); r[1]=(short)f2bf(a[1]);
  r[2]=(short)f2bf(a[2]); r[3]=(short)f2bf(a[3]);
  r[4]=(short)f2bf(b[0]); r[5]=(short)f2bf(b[1]);
  r[6]=(short)f2bf(b[2]); r[7]=(short)f2bf(b[3]);
  return r;
}

__device__ __forceinline__ unsigned long long pack4u64(float4v v){
  return (unsigned long long)f2bf(v[0])
       | ((unsigned long long)f2bf(v[1])<<16)
       | ((unsigned long long)f2bf(v[2])<<32)
       | ((unsigned long long)f2bf(v[3])<<48);
}

// B-fragment for mfma_f32_16x16x32_bf16: lane holds W[n=base+(lane&15)][k0 + 8*(lane>>4) + i]
__device__ __forceinline__ short8v load_wfrag(const float* __restrict__ W, int n, int k0, int ldk){
  const float* p = W + (size_t)n*(size_t)ldk + (size_t)k0;
  float4v a = *(const float4v*)p;
  float4v b = *(const float4v*)(p+4);
  return pack8(a,b);
}

__device__ __forceinline__ float4v mfma16(short8v a, short8v b, float4v c){
  return __builtin_amdgcn_mfma_f32_16x16x32_bf16(a, b, c, 0, 0, 0);
}

__device__ __forceinline__ float sigm(float v){
  return __builtin_amdgcn_rcpf(1.0f + __expf(-v));
}
__device__ __forceinline__ float tanh_(float v){
  return 1.0f - 2.0f*__builtin_amdgcn_rcpf(1.0f + __expf(2.0f*v));
}

// Raw barrier: lgkmcnt-only drain (no vmcnt) so global stores stay in flight.
__device__ __forceinline__ void bar_lds(){
  __builtin_amdgcn_sched_barrier(0);
  asm volatile("s_waitcnt lgkmcnt(0)" ::: "memory");
  __builtin_amdgcn_s_barrier();
  __builtin_amdgcn_sched_barrier(0);
}

// ---------------- precompute: W_eff = dW_hh + dW_ih @ oW ; b_eff = bd + dW_ih @ ob ----------------
__global__ __launch_bounds__(256) void weff_kernel(
    const float* __restrict__ dW_ih, const float* __restrict__ dW_hh,
    const float* __restrict__ db_ih, const float* __restrict__ db_hh,
    const float* __restrict__ oW,    const float* __restrict__ ob,
    float* __restrict__ ws)
{
  int id = blockIdx.x*256 + threadIdx.x;
  if (id < 512*128) {
    int n = id >> 7, h = id & 127;
    float s = dW_hh[id];
    #pragma unroll 8
    for (int d = 0; d < Dn; ++d) s += dW_ih[n*Dn + d] * oW[d*Hn + h];
    ws[id] = s;
  } else if (id < 512*128 + 512) {
    int n = id - 512*128;
    float s = db_ih[n] + db_hh[n];
    #pragma unroll 8
    for (int d = 0; d < Dn; ++d) s += dW_ih[n*Dn + d] * ob[d];
    ws[512*128 + n] = s;
  }
}

// ---------------- main fused kernel ----------------
__global__ __launch_bounds__(256, 1) void vae_fused(
    const float* __restrict__ x,     const float* __restrict__ eps,
    const float* __restrict__ eW_ih, const float* __restrict__ eW_hh,
    const float* __restrict__ eb_ih, const float* __restrict__ eb_hh,
    const float* __restrict__ muW,   const float* __restrict__ mub,
    const float* __restrict__ lvW,   const float* __restrict__ lvb,
    const float* __restrict__ iW,    const float* __restrict__ ib,
    const float* __restrict__ dW_hh, const float* __restrict__ db_ih,
    const float* __restrict__ db_hh, const float* __restrict__ oW,
    const float* __restrict__ ob,    const float* __restrict__ ws,
    float* __restrict__ out)
{
  __shared__ __align__(16) unsigned short x_s[2*Tn*Dn];   // 128 KB: x rows b0,b0+1 as bf16
  __shared__ __align__(16) unsigned short h_lds[2*2*128]; // 2 KB: double-buffered h, 2 rows each
  __shared__ __align__(16) float sc_h[2*Hn];
  __shared__ __align__(16) float sc_mu[2*Ln];
  __shared__ __align__(16) float sc_lv[2*Ln];
  __shared__ __align__(16) float sc_z[2*Ln];

  const int tid  = threadIdx.x;
  const int lane = tid & 63;
  const int w    = tid >> 6;          // wave 0..3: owns h-indices [w*32, w*32+32)
  const int m    = lane & 15;         // fragment col (C) / replicated row (A)
  const int q    = lane >> 4;         // k-group; also selects (half, r) for nonlin
  const int hrow = m & 1;             // real batch row this lane's A-fragment reads
  const int half_= q & 1;             // gate half (which 16-col subtile) this lane owns
  const int r_   = q >> 1;            // batch row this lane owns for nonlin
  const int jown = w*32 + half_*16 + m;  // h-index this lane owns
  const int b0   = blockIdx.x * 2;

  // ---- preload x rows b0,b0+1 -> LDS bf16 (fully coalesced) ----
  {
    const float* xr = x + (size_t)b0 * Tn * Dn;
    #pragma unroll 4
    for (int k2 = 0; k2 < 64; ++k2) {
      int idx4 = tid + k2*256;                       // 16384 float4s
      float4v v = *(const float4v*)(xr + (size_t)idx4*4);
      *(unsigned long long*)((char*)x_s + (size_t)idx4*8) = pack4u64(v);
    }
  }
  // ---- zero h buffers (512 shorts = 256 ints) ----
  ((int*)h_lds)[tid] = 0;

  // ---- encoder weights: tile nt -> row n = (nt>>1)*128 + w*32 + (nt&1)*16 + m ----
  short8v wih[16];   // [nt][kt0..1] : 4H x D
  short8v whh[32];   // [nt][kt0..3] : 4H x H
  #pragma unroll
  for (int nt = 0; nt < 8; ++nt) {
    const int n = (nt>>1)*128 + w*32 + (nt&1)*16 + m;
    #pragma unroll
    for (int kt = 0; kt < 2; ++kt) wih[nt*2+kt] = load_wfrag(eW_ih, n, kt*32 + q*8, Dn);
    #pragma unroll
    for (int kt = 0; kt < 4; ++kt) whh[nt*4+kt] = load_wfrag(eW_hh, n, kt*32 + q*8, Hn);
  }
  float bia[4];   // per-lane biases for the (half_, jown) this lane owns
  #pragma unroll
  for (int g = 0; g < 4; ++g) bia[g] = eb_ih[g*128 + jown] + eb_hh[g*128 + jown];

  float cst = 0.0f, hval = 0.0f;      // per-lane c/h state for (r_, jown)
  __syncthreads();

  // A-fragment reads: row (m&1) replicated across all 16 fragment rows -> C rows 0..15 all real.
#define READ_HFRAG(RB, KB) (*(const short8v*)((const char*)h_lds + (RB)*512 + hrow*256 + (((KB) + q*16) ^ (hrow<<4))))
#define READ_XFRAG(T, KT)  (*(const short8v*)((const char*)x_s + hrow*65536 + (T)*128 + (KT)*64 + q*16))

  // C row (q*4+reg) has parity reg&1 == real row -> every lane holds both rows in regs 0,1.
#define NONLIN_WRITE(ACC, WB) do { \
    float gi = (ACC)[0+half_][r_] + bia[0]; \
    float gf = (ACC)[2+half_][r_] + bia[1]; \
    float gg = (ACC)[4+half_][r_] + bia[2]; \
    float go = (ACC)[6+half_][r_] + bia[3]; \
    float c  = sigm(gf)*cst + sigm(gi)*tanh_(gg); \
    cst = c; \
    hval = sigm(go)*tanh_(c); \
    *(unsigned short*)((char*)h_lds + (WB)*512 + r_*256 + ((2*jown) ^ (r_<<4))) = f2bf(hval); \
  } while(0)

#define ENC_STEP(T, RB) do { \
    short8v hf0 = READ_HFRAG(RB,0),  hf1 = READ_HFRAG(RB,64); \
    short8v hf2 = READ_HFRAG(RB,128), hf3 = READ_HFRAG(RB,192); \
    short8v xf0 = READ_XFRAG(T,0), xf1 = READ_XFRAG(T,1); \
    float4v acc[8]; \
    _Pragma("unroll") \
    for (int nt = 0; nt < 8; ++nt) { \
      float4v a = {0.f,0.f,0.f,0.f}; \
      a = mfma16(xf0, wih[nt*2+0], a); \
      a = mfma16(xf1, wih[nt*2+1], a); \
      a = mfma16(hf0, whh[nt*4+0], a); \
      a = mfma16(hf1, whh[nt*4+1], a); \
      a = mfma16(hf2, whh[nt*4+2], a); \
      a = mfma16(hf3, whh[nt*4+3], a); \
      acc[nt] = a; \
    } \
    NONLIN_WRITE(acc, (RB)^1); \
    __syncthreads(); \
  } while(0)

  // ================= encoder: 512 steps, one barrier per step =================
  for (int t = 0; t < Tn; t += 2) {
    ENC_STEP(t,   0);
    ENC_STEP(t+1, 1);
  }
  // final h in buffer 0; exact f32 copy of owned element in hval

  // ================= latent =================
  sc_h[r_*Hn + jown] = hval;
  __syncthreads();

  if (tid < 128) {
    const int isLv = tid >> 6;
    const int rr   = (tid >> 5) & 1;
    const int l    = tid & 31;
    const float* Wp = isLv ? lvW : muW;
    float s = isLv ? lvb[l] : mub[l];
    #pragma unroll
    for (int k = 0; k < Hn; k += 4) {
      float4v wv = *(const float4v*)(Wp + l*Hn + k);
      float4v hv = *(const float4v*)(sc_h + rr*Hn + k);
      s += wv[0]*hv[0] + wv[1]*hv[1] + wv[2]*hv[2] + wv[3]*hv[3];
    }
    out[(size_t)Bn*Tn*Dn + (size_t)isLv*Bn*Ln + (size_t)(b0+rr)*Ln + l] = s;
    (isLv ? sc_lv : sc_mu)[rr*Ln + l] = s;
  }
  __syncthreads();

  if (tid < 64) {
    int rr = tid >> 5, l = tid & 31;
    sc_z[rr*Ln+l] = sc_mu[rr*Ln+l] + eps[(size_t)(b0+rr)*Ln + l] * __expf(0.5f * sc_lv[rr*Ln+l]);
  }
  __syncthreads();

  { // decoder hidden init -> h buffer 0 (256 threads cover 2 rows x 128)
    int rr = tid >> 7, jj = tid & 127;
    float s = ib[jj];
    #pragma unroll
    for (int l = 0; l < Ln; ++l) s += sc_z[rr*Ln + l] * iW[jj*Ln + l];
    *(unsigned short*)((char*)h_lds + rr*256 + ((2*jj) ^ (rr<<4))) = f2bf(s);
  }
  cst = 0.0f;

  // ---- decoder step-0 weights (dW_hh, biases bd) + output-proj fragments ----
  #pragma unroll
  for (int nt = 0; nt < 8; ++nt) {
    const int n = (nt>>1)*128 + w*32 + (nt&1)*16 + m;
    #pragma unroll
    for (int kt = 0; kt < 4; ++kt) whh[nt*4+kt] = load_wfrag(dW_hh, n, kt*32 + q*8, Hn);
  }
  #pragma unroll
  for (int g = 0; g < 4; ++g) bia[g] = db_ih[g*128 + jown] + db_hh[g*128 + jown];
  short8v ow0 = load_wfrag(oW, w*16+m,  0 + q*8, Hn);
  short8v ow1 = load_wfrag(oW, w*16+m, 32 + q*8, Hn);
  short8v ow2 = load_wfrag(oW, w*16+m, 64 + q*8, Hn);
  short8v ow3 = load_wfrag(oW, w*16+m, 96 + q*8, Hn);
  const float obv = ob[w*16+m];
  __syncthreads();

  // ---- decoder step 0: gates = h0 @ dW_hh^T + bd (input is zero) ----
  {
    short8v hf0 = READ_HFRAG(0,0),  hf1 = READ_HFRAG(0,64);
    short8v hf2 = READ_HFRAG(0,128), hf3 = READ_HFRAG(0,192);
    float4v acc[8];
    #pragma unroll
    for (int nt = 0; nt < 8; ++nt) {
      float4v a = {0.f,0.f,0.f,0.f};
      a = mfma16(hf0, whh[nt*4+0], a);
      a = mfma16(hf1, whh[nt*4+1], a);
      a = mfma16(hf2, whh[nt*4+2], a);
      a = mfma16(hf3, whh[nt*4+3], a);
      acc[nt] = a;
    }
    NONLIN_WRITE(acc, 1);
    __syncthreads();
  }

  // ---- switch to folded weights: W_eff = dW_hh + dW_ih@oW ; b_eff ----
  {
    const float* weff = ws;
    const float* beff = ws + 512*128;
    #pragma unroll
    for (int nt = 0; nt < 8; ++nt) {
      const int n = (nt>>1)*128 + w*32 + (nt&1)*16 + m;
      #pragma unroll
      for (int kt = 0; kt < 4; ++kt) whh[nt*4+kt] = load_wfrag(weff, n, kt*32 + q*8, Hn);
    }
    #pragma unroll
    for (int g = 0; g < 4; ++g) bia[g] = beff[g*128 + jown];
  }

#define DEC_STEP(I, RB) do { \
    short8v hf0 = READ_HFRAG(RB,0),  hf1 = READ_HFRAG(RB,64); \
    short8v hf2 = READ_HFRAG(RB,128), hf3 = READ_HFRAG(RB,192); \
    float4v acc[8]; \
    _Pragma("unroll") \
    for (int nt = 0; nt < 8; ++nt) { \
      float4v a = {0.f,0.f,0.f,0.f}; \
      a = mfma16(hf0, whh[nt*4+0], a); \
      a = mfma16(hf1, whh[nt*4+1], a); \
      a = mfma16(hf2, whh[nt*4+2], a); \
      a = mfma16(hf3, whh[nt*4+3], a); \
      acc[nt] = a; \
    } \
    float4v ya = {0.f,0.f,0.f,0.f}; \
    ya = mfma16(hf0, ow0, ya); ya = mfma16(hf1, ow1, ya); \
    ya = mfma16(hf2, ow2, ya); ya = mfma16(hf3, ow3, ya); \
    if (lane < 16) { \
      out[((size_t)(b0+0)*Tn + (size_t)((I)-1))*Dn + w*16 + lane] = ya[0] + obv; \
      out[((size_t)(b0+1)*Tn + (size_t)((I)-1))*Dn + w*16 + lane] = ya[1] + obv; \
    } \
    NONLIN_WRITE(acc, (RB)^1); \
    bar_lds(); \
  } while(0)

  // ---- decoder steps 1..511; y(i-1) computed from the same h(i) fragments ----
  for (int i = 1; i < Tn-1; i += 2) {
    DEC_STEP(i,   1);
    DEC_STEP(i+1, 0);
  }
  DEC_STEP(Tn-1, 1);

  // ---- epilogue: y(511) from h(512) (buffer 0) ----
  {
    short8v hf0 = READ_HFRAG(0,0),  hf1 = READ_HFRAG(0,64);
    short8v hf2 = READ_HFRAG(0,128), hf3 = READ_HFRAG(0,192);
    float4v ya = {0.f,0.f,0.f,0.f};
    ya = mfma16(hf0, ow0, ya); ya = mfma16(hf1, ow1, ya);
    ya = mfma16(hf2, ow2, ya); ya = mfma16(hf3, ow3, ya);
    if (lane < 16) {
      out[((size_t)(b0+0)*Tn + (size_t)(Tn-1))*Dn + w*16 + lane] = ya[0] + obv;
      out[((size_t)(b0+1)*Tn + (size_t)(Tn-1))*Dn + w*16 + lane] = ya[1] + obv;
    }
  }
#undef DEC_STEP
#undef ENC_STEP
#undef NONLIN_WRITE
#undef READ_HFRAG
#undef READ_XFRAG
}

extern "C" void kernel_launch(void* const* d_in, const int* in_sizes, int n_in,
                              void* d_out, int out_size, void* d_ws, size_t ws_size,
                              hipStream_t stream) {
  (void)in_sizes; (void)n_in; (void)ws_size; (void)out_size;
  const float* x     = (const float*)d_in[0];
  const float* eps   = (const float*)d_in[1];
  const float* eW_ih = (const float*)d_in[2];
  const float* eW_hh = (const float*)d_in[3];
  const float* eb_ih = (const float*)d_in[4];
  const float* eb_hh = (const float*)d_in[5];
  const float* muW   = (const float*)d_in[6];
  const float* mub   = (const float*)d_in[7];
  const float* lvW   = (const float*)d_in[8];
  const float* lvb   = (const float*)d_in[9];
  const float* iW    = (const float*)d_in[10];
  const float* ib    = (const float*)d_in[11];
  const float* dW_ih = (const float*)d_in[12];
  const float* dW_hh = (const float*)d_in[13];
  const float* db_ih = (const float*)d_in[14];
  const float* db_hh = (const float*)d_in[15];
  const float* oW    = (const float*)d_in[16];
  const float* ob    = (const float*)d_in[17];
  float* out = (float*)d_out;
  float* ws  = (float*)d_ws;

  weff_kernel<<<dim3(258), dim3(256), 0, stream>>>(dW_ih, dW_hh, db_ih, db_hh, oW, ob, ws);
  vae_fused<<<dim3(256), dim3(256), 0, stream>>>(
      x, eps, eW_ih, eW_hh, eb_ih, eb_hh, muW, mub, lvW, lvb,
      iW, ib, dW_hh, db_ih, db_hh, oW, ob, ws, out);
}

// Round 4
// 611.117 us; speedup vs baseline: 7.8516x; 7.8516x over previous
//
#include <hip/hip_runtime.h>

#define Bn 512
#define Tn 512
#define Dn 64
#define Hn 128
#define Ln 32

typedef __attribute__((ext_vector_type(8))) short short8v;
typedef __attribute__((ext_vector_type(4))) float float4v;

__device__ __forceinline__ unsigned short f2bf(float f){
  unsigned int u = __float_as_uint(f);
  u += 0x7FFFu + ((u >> 16) & 1u);           // round-to-nearest-even
  return (unsigned short)(u >> 16);
}

__device__ __forceinline__ short8v pack8(float4v a, float4v b){
  short8v r;
  r[0]=(short)f2bf(a[0]); r[1]=(short)f2bf(a[1]);
  r[2]=(short)f2bf(a[2]); r[3]=(short)f2bf(a[3]);
  r[4]=(short)f2bf(b[0]); r[5]=(short)f2bf(b[1]);
  r[6]=(short)f2bf(b[2]); r[7]=(short)f2bf(b[3]);
  return r;
}

__device__ __forceinline__ unsigned long long pack4u64(float4v v){
  return (unsigned long long)f2bf(v[0])
       | ((unsigned long long)f2bf(v[1])<<16)
       | ((unsigned long long)f2bf(v[2])<<32)
       | ((unsigned long long)f2bf(v[3])<<48);
}

// B-fragment for mfma_f32_16x16x32_bf16: lane holds W[n=base+(lane&15)][k0 + 8*(lane>>4) + i]
__device__ __forceinline__ short8v load_wfrag(const float* __restrict__ W, int n, int k0, int ldk){
  const float* p = W + (size_t)n*(size_t)ldk + (size_t)k0;
  float4v a = *(const float4v*)p;
  float4v b = *(const float4v*)(p+4);
  return pack8(a,b);
}

__device__ __forceinline__ float4v mfma16(short8v a, short8v b, float4v c){
  return __builtin_amdgcn_mfma_f32_16x16x32_bf16(a, b, c, 0, 0, 0);
}

__device__ __forceinline__ float sigm(float v){
  return __builtin_amdgcn_rcpf(1.0f + __expf(-v));
}
__device__ __forceinline__ float tanh_(float v){
  return 1.0f - 2.0f*__builtin_amdgcn_rcpf(1.0f + __expf(2.0f*v));
}

// Raw barrier: lgkmcnt-only drain (no vmcnt) so global stores stay in flight.
__device__ __forceinline__ void bar_lds(){
  __builtin_amdgcn_sched_barrier(0);
  asm volatile("s_waitcnt lgkmcnt(0)" ::: "memory");
  __builtin_amdgcn_s_barrier();
  __builtin_amdgcn_sched_barrier(0);
}

// ---------------- precompute: W_eff = dW_hh + dW_ih @ oW ; b_eff = bd + dW_ih @ ob ----------------
__global__ __launch_bounds__(256) void weff_kernel(
    const float* __restrict__ dW_ih, const float* __restrict__ dW_hh,
    const float* __restrict__ db_ih, const float* __restrict__ db_hh,
    const float* __restrict__ oW,    const float* __restrict__ ob,
    float* __restrict__ ws)
{
  int id = blockIdx.x*256 + threadIdx.x;
  if (id < 512*128) {
    int n = id >> 7, h = id & 127;
    float s = dW_hh[id];
    #pragma unroll 8
    for (int d = 0; d < Dn; ++d) s += dW_ih[n*Dn + d] * oW[d*Hn + h];
    ws[id] = s;
  } else if (id < 512*128 + 512) {
    int n = id - 512*128;
    float s = db_ih[n] + db_hh[n];
    #pragma unroll 8
    for (int d = 0; d < Dn; ++d) s += dW_ih[n*Dn + d] * ob[d];
    ws[512*128 + n] = s;
  }
}

// ---------------- main fused kernel ----------------
__global__ __launch_bounds__(256, 1) void vae_fused(
    const float* __restrict__ x,     const float* __restrict__ eps,
    const float* __restrict__ eW_ih, const float* __restrict__ eW_hh,
    const float* __restrict__ eb_ih, const float* __restrict__ eb_hh,
    const float* __restrict__ muW,   const float* __restrict__ mub,
    const float* __restrict__ lvW,   const float* __restrict__ lvb,
    const float* __restrict__ iW,    const float* __restrict__ ib,
    const float* __restrict__ dW_hh, const float* __restrict__ db_ih,
    const float* __restrict__ db_hh, const float* __restrict__ oW,
    const float* __restrict__ ob,    const float* __restrict__ ws,
    float* __restrict__ out)
{
  __shared__ __align__(16) unsigned short x_s[2*Tn*Dn];   // 128 KB: x rows b0,b0+1 as bf16
  __shared__ __align__(16) unsigned short h_lds[2*2*128]; // 2 KB: double-buffered h, 2 rows each
  __shared__ __align__(16) float sc_h[2*Hn];
  __shared__ __align__(16) float sc_mu[2*Ln];
  __shared__ __align__(16) float sc_lv[2*Ln];
  __shared__ __align__(16) float sc_z[2*Ln];

  const int tid  = threadIdx.x;
  const int lane = tid & 63;
  const int w    = tid >> 6;          // wave 0..3: owns h-indices [w*32, w*32+32)
  const int m    = lane & 15;         // fragment col (C) / replicated row (A)
  const int q    = lane >> 4;         // k-group; also selects (half, r) for nonlin
  const int hrow = m & 1;             // real batch row this lane's A-fragment reads
  const int half_= q & 1;             // gate half (which 16-col subtile) this lane owns
  const int r_   = q >> 1;            // batch row this lane owns for nonlin
  const int jown = w*32 + half_*16 + m;  // h-index this lane owns
  const int b0   = blockIdx.x * 2;
  // precomputed per-lane addresses (all compile-time-shaped, runtime lane-uniform values)
  const int hw_off  = r_*256 + ((2*jown) ^ (r_<<4));       // nonlin h-write byte offset (within buffer)
  const int hr_base = hrow*256;                            // h-frag read base
  const int hr_col  = (q*16) ^ (hrow<<4);                  // h-frag read column offset

  // ---- preload x rows b0,b0+1 -> LDS bf16 (fully coalesced) ----
  {
    const float* xr = x + (size_t)b0 * Tn * Dn;
    #pragma unroll 4
    for (int k2 = 0; k2 < 64; ++k2) {
      int idx4 = tid + k2*256;                       // 16384 float4s
      float4v v = *(const float4v*)(xr + (size_t)idx4*4);
      *(unsigned long long*)((char*)x_s + (size_t)idx4*8) = pack4u64(v);
    }
  }
  // ---- zero h buffers (512 shorts = 256 ints) ----
  ((int*)h_lds)[tid] = 0;

  // ---- encoder weights: tile nt -> row n = (nt>>1)*128 + w*32 + (nt&1)*16 + m ----
  short8v wih[16];   // [nt][kt0..1] : 4H x D
  short8v whh[32];   // [nt][kt0..3] : 4H x H
  #pragma unroll
  for (int nt = 0; nt < 8; ++nt) {
    const int n = (nt>>1)*128 + w*32 + (nt&1)*16 + m;
    #pragma unroll
    for (int kt = 0; kt < 2; ++kt) wih[nt*2+kt] = load_wfrag(eW_ih, n, kt*32 + q*8, Dn);
    #pragma unroll
    for (int kt = 0; kt < 4; ++kt) whh[nt*4+kt] = load_wfrag(eW_hh, n, kt*32 + q*8, Hn);
  }
  float bia[4];   // per-lane biases for the (half_, jown) this lane owns
  #pragma unroll
  for (int g = 0; g < 4; ++g) bia[g] = eb_ih[g*128 + jown] + eb_hh[g*128 + jown];

  float cst = 0.0f, hval = 0.0f;      // per-lane c/h state for (r_, jown)
  __syncthreads();

  // A-fragment reads: row (m&1) replicated across all 16 fragment rows -> C rows 0..15 all real.
#define READ_HFRAG(RB, KB) (*(const short8v*)((const char*)h_lds + (RB)*512 + hr_base + (KB) + hr_col))
#define READ_XFRAG(T, KT)  (*(const short8v*)((const char*)x_s + hrow*65536 + (T)*128 + (KT)*64 + q*16))

  // Gate extraction with COMPILE-TIME indices only (rule #20: no runtime-indexed
  // ext_vector arrays -> scratch). half_/r_ selection via cndmask ternaries.
  // C row (q*4+reg) parity reg&1 == batch row; reg 0/1 = rows r=0/1 for every lane.
#define NONLIN_WRITE(ACC, WB) do { \
    float gi = half_ ? (r_ ? (ACC)[1][1] : (ACC)[1][0]) : (r_ ? (ACC)[0][1] : (ACC)[0][0]); \
    float gf = half_ ? (r_ ? (ACC)[3][1] : (ACC)[3][0]) : (r_ ? (ACC)[2][1] : (ACC)[2][0]); \
    float gg = half_ ? (r_ ? (ACC)[5][1] : (ACC)[5][0]) : (r_ ? (ACC)[4][1] : (ACC)[4][0]); \
    float go = half_ ? (r_ ? (ACC)[7][1] : (ACC)[7][0]) : (r_ ? (ACC)[6][1] : (ACC)[6][0]); \
    gi += bia[0]; gf += bia[1]; gg += bia[2]; go += bia[3]; \
    float c  = sigm(gf)*cst + sigm(gi)*tanh_(gg); \
    cst = c; \
    hval = sigm(go)*tanh_(c); \
    *(unsigned short*)((char*)h_lds + (WB)*512 + hw_off) = f2bf(hval); \
  } while(0)

#define ENC_STEP(T, RB) do { \
    short8v hf0 = READ_HFRAG(RB,0),  hf1 = READ_HFRAG(RB,64); \
    short8v hf2 = READ_HFRAG(RB,128), hf3 = READ_HFRAG(RB,192); \
    short8v xf0 = READ_XFRAG(T,0), xf1 = READ_XFRAG(T,1); \
    float4v acc[8]; \
    _Pragma("unroll") \
    for (int nt = 0; nt < 8; ++nt) { \
      float4v a = {0.f,0.f,0.f,0.f}; \
      a = mfma16(xf0, wih[nt*2+0], a); \
      a = mfma16(xf1, wih[nt*2+1], a); \
      a = mfma16(hf0, whh[nt*4+0], a); \
      a = mfma16(hf1, whh[nt*4+1], a); \
      a = mfma16(hf2, whh[nt*4+2], a); \
      a = mfma16(hf3, whh[nt*4+3], a); \
      acc[nt] = a; \
    } \
    NONLIN_WRITE(acc, (RB)^1); \
    __syncthreads(); \
  } while(0)

  // ================= encoder: 512 steps, one barrier per step =================
  for (int t = 0; t < Tn; t += 2) {
    ENC_STEP(t,   0);
    ENC_STEP(t+1, 1);
  }
  // final h in buffer 0; exact f32 copy of owned element in hval

  // ================= latent =================
  sc_h[r_*Hn + jown] = hval;
  __syncthreads();

  if (tid < 128) {
    const int isLv = tid >> 6;
    const int rr   = (tid >> 5) & 1;
    const int l    = tid & 31;
    const float* Wp = isLv ? lvW : muW;
    float s = isLv ? lvb[l] : mub[l];
    #pragma unroll
    for (int k = 0; k < Hn; k += 4) {
      float4v wv = *(const float4v*)(Wp + l*Hn + k);
      float4v hv = *(const float4v*)(sc_h + rr*Hn + k);
      s += wv[0]*hv[0] + wv[1]*hv[1] + wv[2]*hv[2] + wv[3]*hv[3];
    }
    out[(size_t)Bn*Tn*Dn + (size_t)isLv*Bn*Ln + (size_t)(b0+rr)*Ln + l] = s;
    (isLv ? sc_lv : sc_mu)[rr*Ln + l] = s;
  }
  __syncthreads();

  if (tid < 64) {
    int rr = tid >> 5, l = tid & 31;
    sc_z[rr*Ln+l] = sc_mu[rr*Ln+l] + eps[(size_t)(b0+rr)*Ln + l] * __expf(0.5f * sc_lv[rr*Ln+l]);
  }
  __syncthreads();

  { // decoder hidden init -> h buffer 0 (256 threads cover 2 rows x 128)
    int rr = tid >> 7, jj = tid & 127;
    float s = ib[jj];
    #pragma unroll
    for (int l = 0; l < Ln; ++l) s += sc_z[rr*Ln + l] * iW[jj*Ln + l];
    *(unsigned short*)((char*)h_lds + rr*256 + ((2*jj) ^ (rr<<4))) = f2bf(s);
  }
  cst = 0.0f;

  // ---- decoder step-0 weights (dW_hh, biases bd) + output-proj fragments ----
  #pragma unroll
  for (int nt = 0; nt < 8; ++nt) {
    const int n = (nt>>1)*128 + w*32 + (nt&1)*16 + m;
    #pragma unroll
    for (int kt = 0; kt < 4; ++kt) whh[nt*4+kt] = load_wfrag(dW_hh, n, kt*32 + q*8, Hn);
  }
  #pragma unroll
  for (int g = 0; g < 4; ++g) bia[g] = db_ih[g*128 + jown] + db_hh[g*128 + jown];
  short8v ow0 = load_wfrag(oW, w*16+m,  0 + q*8, Hn);
  short8v ow1 = load_wfrag(oW, w*16+m, 32 + q*8, Hn);
  short8v ow2 = load_wfrag(oW, w*16+m, 64 + q*8, Hn);
  short8v ow3 = load_wfrag(oW, w*16+m, 96 + q*8, Hn);
  const float obv = ob[w*16+m];
  __syncthreads();

  // ---- decoder step 0: gates = h0 @ dW_hh^T + bd (input is zero) ----
  {
    short8v hf0 = READ_HFRAG(0,0),  hf1 = READ_HFRAG(0,64);
    short8v hf2 = READ_HFRAG(0,128), hf3 = READ_HFRAG(0,192);
    float4v acc[8];
    #pragma unroll
    for (int nt = 0; nt < 8; ++nt) {
      float4v a = {0.f,0.f,0.f,0.f};
      a = mfma16(hf0, whh[nt*4+0], a);
      a = mfma16(hf1, whh[nt*4+1], a);
      a = mfma16(hf2, whh[nt*4+2], a);
      a = mfma16(hf3, whh[nt*4+3], a);
      acc[nt] = a;
    }
    NONLIN_WRITE(acc, 1);
    __syncthreads();
  }

  // ---- switch to folded weights: W_eff = dW_hh + dW_ih@oW ; b_eff ----
  {
    const float* weff = ws;
    const float* beff = ws + 512*128;
    #pragma unroll
    for (int nt = 0; nt < 8; ++nt) {
      const int n = (nt>>1)*128 + w*32 + (nt&1)*16 + m;
      #pragma unroll
      for (int kt = 0; kt < 4; ++kt) whh[nt*4+kt] = load_wfrag(weff, n, kt*32 + q*8, Hn);
    }
    #pragma unroll
    for (int g = 0; g < 4; ++g) bia[g] = beff[g*128 + jown];
  }

#define DEC_STEP(I, RB) do { \
    short8v hf0 = READ_HFRAG(RB,0),  hf1 = READ_HFRAG(RB,64); \
    short8v hf2 = READ_HFRAG(RB,128), hf3 = READ_HFRAG(RB,192); \
    float4v acc[8]; \
    _Pragma("unroll") \
    for (int nt = 0; nt < 8; ++nt) { \
      float4v a = {0.f,0.f,0.f,0.f}; \
      a = mfma16(hf0, whh[nt*4+0], a); \
      a = mfma16(hf1, whh[nt*4+1], a); \
      a = mfma16(hf2, whh[nt*4+2], a); \
      a = mfma16(hf3, whh[nt*4+3], a); \
      acc[nt] = a; \
    } \
    float4v ya = {0.f,0.f,0.f,0.f}; \
    ya = mfma16(hf0, ow0, ya); ya = mfma16(hf1, ow1, ya); \
    ya = mfma16(hf2, ow2, ya); ya = mfma16(hf3, ow3, ya); \
    if (lane < 16) { \
      out[((size_t)(b0+0)*Tn + (size_t)((I)-1))*Dn + w*16 + lane] = ya[0] + obv; \
      out[((size_t)(b0+1)*Tn + (size_t)((I)-1))*Dn + w*16 + lane] = ya[1] + obv; \
    } \
    NONLIN_WRITE(acc, (RB)^1); \
    bar_lds(); \
  } while(0)

  // ---- decoder steps 1..511; y(i-1) computed from the same h(i) fragments ----
  for (int i = 1; i < Tn-1; i += 2) {
    DEC_STEP(i,   1);
    DEC_STEP(i+1, 0);
  }
  DEC_STEP(Tn-1, 1);

  // ---- epilogue: y(511) from h(512) (buffer 0) ----
  {
    short8v hf0 = READ_HFRAG(0,0),  hf1 = READ_HFRAG(0,64);
    short8v hf2 = READ_HFRAG(0,128), hf3 = READ_HFRAG(0,192);
    float4v ya = {0.f,0.f,0.f,0.f};
    ya = mfma16(hf0, ow0, ya); ya = mfma16(hf1, ow1, ya);
    ya = mfma16(hf2, ow2, ya); ya = mfma16(hf3, ow3, ya);
    if (lane < 16) {
      out[((size_t)(b0+0)*Tn + (size_t)(Tn-1))*Dn + w*16 + lane] = ya[0] + obv;
      out[((size_t)(b0+1)*Tn + (size_t)(Tn-1))*Dn + w*16 + lane] = ya[1] + obv;
    }
  }
#undef DEC_STEP
#undef ENC_STEP
#undef NONLIN_WRITE
#undef READ_HFRAG
#undef READ_XFRAG
}

extern "C" void kernel_launch(void* const* d_in, const int* in_sizes, int n_in,
                              void* d_out, int out_size, void* d_ws, size_t ws_size,
                              hipStream_t stream) {
  (void)in_sizes; (void)n_in; (void)ws_size; (void)out_size;
  const float* x     = (const float*)d_in[0];
  const float* eps   = (const float*)d_in[1];
  const float* eW_ih = (const float*)d_in[2];
  const float* eW_hh = (const float*)d_in[3];
  const float* eb_ih = (const float*)d_in[4];
  const float* eb_hh = (const float*)d_in[5];
  const float* muW   = (const float*)d_in[6];
  const float* mub   = (const float*)d_in[7];
  const float* lvW   = (const float*)d_in[8];
  const float* lvb   = (const float*)d_in[9];
  const float* iW    = (const float*)d_in[10];
  const float* ib    = (const float*)d_in[11];
  const float* dW_ih = (const float*)d_in[12];
  const float* dW_hh = (const float*)d_in[13];
  const float* db_ih = (const float*)d_in[14];
  const float* db_hh = (const float*)d_in[15];
  const float* oW    = (const float*)d_in[16];
  const float* ob    = (const float*)d_in[17];
  float* out = (float*)d_out;
  float* ws  = (float*)d_ws;

  weff_kernel<<<dim3(258), dim3(256), 0, stream>>>(dW_ih, dW_hh, db_ih, db_hh, oW, ob, ws);
  vae_fused<<<dim3(256), dim3(256), 0, stream>>>(
      x, eps, eW_ih, eW_hh, eb_ih, eb_hh, muW, mub, lvW, lvb,
      iW, ib, dW_hh, db_ih, db_hh, oW, ob, ws, out);
}

// Round 6
// 609.578 us; speedup vs baseline: 7.8714x; 1.0025x over previous
//
#include <hip/hip_runtime.h>

#define Bn 512
#define Tn 512
#define Dn 64
#define Hn 128
#define Ln 32

typedef __attribute__((ext_vector_type(8))) short short8v;
typedef __attribute__((ext_vector_type(4))) float float4v;

__device__ __forceinline__ unsigned short f2bf(float f){
  unsigned int u = __float_as_uint(f);
  u += 0x7FFFu + ((u >> 16) & 1u);           // round-to-nearest-even
  return (unsigned short)(u >> 16);
}

__device__ __forceinline__ short8v pack8(float4v a, float4v b){
  short8v r;
  r[0]=(short)f2bf(a[0]); r[1]=(short)f2bf(a[1]);
  r[2]=(short)f2bf(a[2]); r[3]=(short)f2bf(a[3]);
  r[4]=(short)f2bf(b[0]); r[5]=(short)f2bf(b[1]);
  r[6]=(short)f2bf(b[2]); r[7]=(short)f2bf(b[3]);
  return r;
}

__device__ __forceinline__ unsigned long long pack4u64(float4v v){
  return (unsigned long long)f2bf(v[0])
       | ((unsigned long long)f2bf(v[1])<<16)
       | ((unsigned long long)f2bf(v[2])<<32)
       | ((unsigned long long)f2bf(v[3])<<48);
}

// B-fragment for mfma_f32_16x16x32_bf16: lane holds W[n=base+(lane&15)][k0 + 8*(lane>>4) + i]
__device__ __forceinline__ short8v load_wfrag(const float* __restrict__ W, int n, int k0, int ldk){
  const float* p = W + (size_t)n*(size_t)ldk + (size_t)k0;
  float4v a = *(const float4v*)p;
  float4v b = *(const float4v*)(p+4);
  return pack8(a,b);
}

__device__ __forceinline__ float4v mfma16(short8v a, short8v b, float4v c){
  return __builtin_amdgcn_mfma_f32_16x16x32_bf16(a, b, c, 0, 0, 0);
}

__device__ __forceinline__ float sigm(float v){
  return __builtin_amdgcn_rcpf(1.0f + __expf(-v));
}
__device__ __forceinline__ float tanh_(float v){
  return 1.0f - 2.0f*__builtin_amdgcn_rcpf(1.0f + __expf(2.0f*v));
}

// Raw barrier: lgkmcnt-only drain (no vmcnt) so global stores stay in flight.
__device__ __forceinline__ void bar_lds(){
  __builtin_amdgcn_sched_barrier(0);
  asm volatile("s_waitcnt lgkmcnt(0)" ::: "memory");
  __builtin_amdgcn_s_barrier();
  __builtin_amdgcn_sched_barrier(0);
}

// ---------------- precompute: W_eff = dW_hh + dW_ih @ oW ; b_eff = bd + dW_ih @ ob ----------------
__global__ __launch_bounds__(256) void weff_kernel(
    const float* __restrict__ dW_ih, const float* __restrict__ dW_hh,
    const float* __restrict__ db_ih, const float* __restrict__ db_hh,
    const float* __restrict__ oW,    const float* __restrict__ ob,
    float* __restrict__ ws)
{
  int id = blockIdx.x*256 + threadIdx.x;
  if (id < 512*128) {
    int n = id >> 7, h = id & 127;
    float s = dW_hh[id];
    #pragma unroll 8
    for (int d = 0; d < Dn; ++d) s += dW_ih[n*Dn + d] * oW[d*Hn + h];
    ws[id] = s;
  } else if (id < 512*128 + 512) {
    int n = id - 512*128;
    float s = db_ih[n] + db_hh[n];
    #pragma unroll 8
    for (int d = 0; d < Dn; ++d) s += dW_ih[n*Dn + d] * ob[d];
    ws[512*128 + n] = s;
  }
}

// ---------------- main fused kernel ----------------
__global__ __launch_bounds__(256, 1) void vae_fused(
    const float* __restrict__ x,     const float* __restrict__ eps,
    const float* __restrict__ eW_ih, const float* __restrict__ eW_hh,
    const float* __restrict__ eb_ih, const float* __restrict__ eb_hh,
    const float* __restrict__ muW,   const float* __restrict__ mub,
    const float* __restrict__ lvW,   const float* __restrict__ lvb,
    const float* __restrict__ iW,    const float* __restrict__ ib,
    const float* __restrict__ dW_hh, const float* __restrict__ db_ih,
    const float* __restrict__ db_hh, const float* __restrict__ oW,
    const float* __restrict__ ob,    const float* __restrict__ ws,
    float* __restrict__ out)
{
  __shared__ __align__(16) unsigned short x_s[2*Tn*Dn];   // 128 KB: x rows b0,b0+1 as bf16
  __shared__ __align__(16) unsigned short h_lds[2*2*128]; // 2 KB: double-buffered h, 2 rows each
  __shared__ __align__(16) float sc_h[2*Hn];
  __shared__ __align__(16) float sc_mu[2*Ln];
  __shared__ __align__(16) float sc_lv[2*Ln];
  __shared__ __align__(16) float sc_z[2*Ln];

  const int tid  = threadIdx.x;
  const int lane = tid & 63;
  const int w    = tid >> 6;          // wave 0..3: owns h-indices [w*32, w*32+32)
  const int m    = lane & 15;         // fragment col (C) / replicated row (A)
  const int q    = lane >> 4;         // k-group; also selects (half, r) for nonlin
  const int hrow = m & 1;             // real batch row this lane's A-fragment reads
  const int half_= q & 1;             // gate half (which 16-col subtile) this lane owns
  const int r_   = q >> 1;            // batch row this lane owns for nonlin
  const int jown = w*32 + half_*16 + m;  // h-index this lane owns
  const int b0   = blockIdx.x * 2;
  // precomputed per-lane LDS pointers
  char* const hw_p  = (char*)h_lds + r_*256 + ((2*jown) ^ (r_<<4));   // nonlin h-write (buffer 0)
  const char* const hr_p = (const char*)h_lds + hrow*256 + ((q*16) ^ (hrow<<4)); // h-frag read (buffer 0)
  const char* const xr_p = (const char*)x_s + hrow*65536 + q*16;      // x-frag read base

  // ---- preload x rows b0,b0+1 -> LDS bf16 (fully coalesced) ----
  {
    const float* xr = x + (size_t)b0 * Tn * Dn;
    #pragma unroll 4
    for (int k2 = 0; k2 < 64; ++k2) {
      int idx4 = tid + k2*256;                       // 16384 float4s
      float4v v = *(const float4v*)(xr + (size_t)idx4*4);
      *(unsigned long long*)((char*)x_s + (size_t)idx4*8) = pack4u64(v);
    }
  }
  // ---- zero h buffers (512 shorts = 256 ints) ----
  ((int*)h_lds)[tid] = 0;

  // ---- encoder weights: tile nt -> row n = (nt>>1)*128 + w*32 + (nt&1)*16 + m ----
  short8v wih[16];   // [nt][kt0..1] : 4H x D
  short8v whh[32];   // [nt][kt0..3] : 4H x H
  #pragma unroll
  for (int nt = 0; nt < 8; ++nt) {
    const int n = (nt>>1)*128 + w*32 + (nt&1)*16 + m;
    #pragma unroll
    for (int kt = 0; kt < 2; ++kt) wih[nt*2+kt] = load_wfrag(eW_ih, n, kt*32 + q*8, Dn);
    #pragma unroll
    for (int kt = 0; kt < 4; ++kt) whh[nt*4+kt] = load_wfrag(eW_hh, n, kt*32 + q*8, Hn);
  }
  float bia[4];   // per-lane biases for the (half_, jown) this lane owns
  #pragma unroll
  for (int g = 0; g < 4; ++g) bia[g] = eb_ih[g*128 + jown] + eb_hh[g*128 + jown];

  float cst = 0.0f, hval = 0.0f;      // per-lane c/h state for (r_, jown)
  __syncthreads();

  // A-fragment reads: row (m&1) replicated across all 16 fragment rows -> C rows 0..15 all real.
#define READ_HFRAG(RB, KB) (*(const short8v*)(hr_p + (RB)*512 + (KB)))
#define READ_XFRAG(T, KT)  (*(const short8v*)(xr_p + (T)*128 + (KT)*64))

  // Gate extraction with COMPILE-TIME indices only (rule #20). half_/r_ via cndmask.
#define NONLIN_WRITE(ACC, WB) do { \
    float gi = half_ ? (r_ ? (ACC)[1][1] : (ACC)[1][0]) : (r_ ? (ACC)[0][1] : (ACC)[0][0]); \
    float gf = half_ ? (r_ ? (ACC)[3][1] : (ACC)[3][0]) : (r_ ? (ACC)[2][1] : (ACC)[2][0]); \
    float gg = half_ ? (r_ ? (ACC)[5][1] : (ACC)[5][0]) : (r_ ? (ACC)[4][1] : (ACC)[4][0]); \
    float go = half_ ? (r_ ? (ACC)[7][1] : (ACC)[7][0]) : (r_ ? (ACC)[6][1] : (ACC)[6][0]); \
    gi += bia[0]; gf += bia[1]; gg += bia[2]; go += bia[3]; \
    float c  = sigm(gf)*cst + sigm(gi)*tanh_(gg); \
    cst = c; \
    hval = sigm(go)*tanh_(c); \
    *(unsigned short*)(hw_p + (WB)*512) = f2bf(hval); \
  } while(0)

  // k-major MFMA interleave: 8 independent nt chains alternate so no dependent
  // back-to-back MFMAs (1 wave/SIMD has no TLP to hide MFMA result latency).
#define KSLOT(AF, KI) \
    _Pragma("unroll") \
    for (int nt = 0; nt < 8; ++nt) acc[nt] = mfma16((AF), whh[nt*4+(KI)], acc[nt]);

#define ENC_STEP(T, RB) do { \
    short8v hf0 = READ_HFRAG(RB,0),  hf1 = READ_HFRAG(RB,64); \
    short8v hf2 = READ_HFRAG(RB,128), hf3 = READ_HFRAG(RB,192); \
    short8v xf0 = READ_XFRAG(T,0), xf1 = READ_XFRAG(T,1); \
    float4v acc[8]; \
    _Pragma("unroll") \
    for (int nt = 0; nt < 8; ++nt) { \
      float4v z = {0.f,0.f,0.f,0.f}; \
      acc[nt] = mfma16(xf0, wih[nt*2+0], z); \
    } \
    _Pragma("unroll") \
    for (int nt = 0; nt < 8; ++nt) acc[nt] = mfma16(xf1, wih[nt*2+1], acc[nt]); \
    KSLOT(hf0, 0) KSLOT(hf1, 1) KSLOT(hf2, 2) KSLOT(hf3, 3) \
    NONLIN_WRITE(acc, (RB)^1); \
    __syncthreads(); \
  } while(0)

  // ================= encoder: 512 steps, one barrier per step =================
  for (int t = 0; t < Tn; t += 2) {
    ENC_STEP(t,   0);
    ENC_STEP(t+1, 1);
  }
  // final h in buffer 0; exact f32 copy of owned element in hval

  // ================= latent =================
  sc_h[r_*Hn + jown] = hval;
  __syncthreads();

  if (tid < 128) {
    const int isLv = tid >> 6;
    const int rr   = (tid >> 5) & 1;
    const int l    = tid & 31;
    const float* Wp = isLv ? lvW : muW;
    float s = isLv ? lvb[l] : mub[l];
    #pragma unroll
    for (int k = 0; k < Hn; k += 4) {
      float4v wv = *(const float4v*)(Wp + l*Hn + k);
      float4v hv = *(const float4v*)(sc_h + rr*Hn + k);
      s += wv[0]*hv[0] + wv[1]*hv[1] + wv[2]*hv[2] + wv[3]*hv[3];
    }
    out[(size_t)Bn*Tn*Dn + (size_t)isLv*Bn*Ln + (size_t)(b0+rr)*Ln + l] = s;
    (isLv ? sc_lv : sc_mu)[rr*Ln + l] = s;
  }
  __syncthreads();

  if (tid < 64) {
    int rr = tid >> 5, l = tid & 31;
    sc_z[rr*Ln+l] = sc_mu[rr*Ln+l] + eps[(size_t)(b0+rr)*Ln + l] * __expf(0.5f * sc_lv[rr*Ln+l]);
  }
  __syncthreads();

  { // decoder hidden init -> h buffer 0 (256 threads cover 2 rows x 128)
    int rr = tid >> 7, jj = tid & 127;
    float s = ib[jj];
    #pragma unroll
    for (int l = 0; l < Ln; ++l) s += sc_z[rr*Ln + l] * iW[jj*Ln + l];
    *(unsigned short*)((char*)h_lds + rr*256 + ((2*jj) ^ (rr<<4))) = f2bf(s);
  }
  cst = 0.0f;

  // ---- decoder step-0 weights (dW_hh, biases bd) + output-proj fragments ----
  #pragma unroll
  for (int nt = 0; nt < 8; ++nt) {
    const int n = (nt>>1)*128 + w*32 + (nt&1)*16 + m;
    #pragma unroll
    for (int kt = 0; kt < 4; ++kt) whh[nt*4+kt] = load_wfrag(dW_hh, n, kt*32 + q*8, Hn);
  }
  #pragma unroll
  for (int g = 0; g < 4; ++g) bia[g] = db_ih[g*128 + jown] + db_hh[g*128 + jown];
  short8v ow0 = load_wfrag(oW, w*16+m,  0 + q*8, Hn);
  short8v ow1 = load_wfrag(oW, w*16+m, 32 + q*8, Hn);
  short8v ow2 = load_wfrag(oW, w*16+m, 64 + q*8, Hn);
  short8v ow3 = load_wfrag(oW, w*16+m, 96 + q*8, Hn);
  const float obv = ob[w*16+m];
  __syncthreads();

  // ---- decoder step 0: gates = h0 @ dW_hh^T + bd (input is zero) ----
  {
    short8v hf0 = READ_HFRAG(0,0),  hf1 = READ_HFRAG(0,64);
    short8v hf2 = READ_HFRAG(0,128), hf3 = READ_HFRAG(0,192);
    float4v acc[8];
    #pragma unroll
    for (int nt = 0; nt < 8; ++nt) {
      float4v z = {0.f,0.f,0.f,0.f};
      acc[nt] = mfma16(hf0, whh[nt*4+0], z);
    }
    KSLOT(hf1, 1) KSLOT(hf2, 2) KSLOT(hf3, 3)
    NONLIN_WRITE(acc, 1);
    __syncthreads();
  }

  // ---- switch to folded weights: W_eff = dW_hh + dW_ih@oW ; b_eff ----
  {
    const float* weff = ws;
    const float* beff = ws + 512*128;
    #pragma unroll
    for (int nt = 0; nt < 8; ++nt) {
      const int n = (nt>>1)*128 + w*32 + (nt&1)*16 + m;
      #pragma unroll
      for (int kt = 0; kt < 4; ++kt) whh[nt*4+kt] = load_wfrag(weff, n, kt*32 + q*8, Hn);
    }
    #pragma unroll
    for (int g = 0; g < 4; ++g) bia[g] = beff[g*128 + jown];
  }

  // running output pointers (strength-reduced; advance by Dn per step)
  float* outp0 = out + (size_t)(b0+0)*Tn*Dn;
  float* outp1 = out + (size_t)(b0+1)*Tn*Dn;
  const int ocol = w*16 + lane;   // valid when lane<16

  // k-major with the y-projection chain folded into the same interleave
#define DEC_STEP(RB) do { \
    short8v hf0 = READ_HFRAG(RB,0),  hf1 = READ_HFRAG(RB,64); \
    short8v hf2 = READ_HFRAG(RB,128), hf3 = READ_HFRAG(RB,192); \
    float4v acc[8]; float4v ya; \
    { float4v z = {0.f,0.f,0.f,0.f}; \
      _Pragma("unroll") \
      for (int nt = 0; nt < 8; ++nt) acc[nt] = mfma16(hf0, whh[nt*4+0], z); \
      ya = mfma16(hf0, ow0, z); } \
    KSLOT(hf1, 1) ya = mfma16(hf1, ow1, ya); \
    KSLOT(hf2, 2) ya = mfma16(hf2, ow2, ya); \
    KSLOT(hf3, 3) ya = mfma16(hf3, ow3, ya); \
    if (lane < 16) { \
      outp0[ocol] = ya[0] + obv; \
      outp1[ocol] = ya[1] + obv; \
    } \
    outp0 += Dn; outp1 += Dn; \
    NONLIN_WRITE(acc, (RB)^1); \
    bar_lds(); \
  } while(0)

  // ---- decoder steps 1..511; y(i-1) computed from the same h(i) fragments ----
  for (int i = 1; i < Tn-1; i += 2) {
    DEC_STEP(1);
    DEC_STEP(0);
  }
  DEC_STEP(1);

  // ---- epilogue: y(511) from h(512) (buffer 0) ----
  {
    short8v hf0 = READ_HFRAG(0,0),  hf1 = READ_HFRAG(0,64);
    short8v hf2 = READ_HFRAG(0,128), hf3 = READ_HFRAG(0,192);
    float4v ya = {0.f,0.f,0.f,0.f};
    ya = mfma16(hf0, ow0, ya); ya = mfma16(hf1, ow1, ya);
    ya = mfma16(hf2, ow2, ya); ya = mfma16(hf3, ow3, ya);
    if (lane < 16) {
      outp0[ocol] = ya[0] + obv;
      outp1[ocol] = ya[1] + obv;
    }
  }
#undef DEC_STEP
#undef ENC_STEP
#undef KSLOT
#undef NONLIN_WRITE
#undef READ_HFRAG
#undef READ_XFRAG
}

extern "C" void kernel_launch(void* const* d_in, const int* in_sizes, int n_in,
                              void* d_out, int out_size, void* d_ws, size_t ws_size,
                              hipStream_t stream) {
  (void)in_sizes; (void)n_in; (void)ws_size; (void)out_size;
  const float* x     = (const float*)d_in[0];
  const float* eps   = (const float*)d_in[1];
  const float* eW_ih = (const float*)d_in[2];
  const float* eW_hh = (const float*)d_in[3];
  const float* eb_ih = (const float*)d_in[4];
  const float* eb_hh = (const float*)d_in[5];
  const float* muW   = (const float*)d_in[6];
  const float* mub   = (const float*)d_in[7];
  const float* lvW   = (const float*)d_in[8];
  const float* lvb   = (const float*)d_in[9];
  const float* iW    = (const float*)d_in[10];
  const float* ib    = (const float*)d_in[11];
  const float* dW_ih = (const float*)d_in[12];
  const float* dW_hh = (const float*)d_in[13];
  const float* db_ih = (const float*)d_in[14];
  const float* db_hh = (const float*)d_in[15];
  const float* oW    = (const float*)d_in[16];
  const float* ob    = (const float*)d_in[17];
  float* out = (float*)d_out;
  float* ws  = (float*)d_ws;

  weff_kernel<<<dim3(258), dim3(256), 0, stream>>>(dW_ih, dW_hh, db_ih, db_hh, oW, ob, ws);
  vae_fused<<<dim3(256), dim3(256), 0, stream>>>(
      x, eps, eW_ih, eW_hh, eb_ih, eb_hh, muW, mub, lvW, lvb,
      iW, ib, dW_hh, db_ih, db_hh, oW, ob, ws, out);
}